// Round 1
// baseline (1007.007 us; speedup 1.0000x reference)
//
#include <hip/hip_runtime.h>

// Fused ReconstructionHead: h = x[:, :-1] @ W1^T + b1; LayerNorm(h)*gamma+beta;
// relu; out[b,t] = dot(h[b,t,:], Wout[t,:]) + bout[t].
// M = 256*512 rows, K = N = 512. bf16 MFMA (16x16x32), fp32 accumulate.
//
// Per WG (256 thr, 4 waves): 32 rows x 512 cols, full K loop, BK=32 chunks,
// A/B staged to LDS as bf16 with register prefetch of chunk c+1 during compute
// of chunk c. LDS rows padded to 40 bf16 (80 B stride) -> 2-way bank aliasing
// only (free). LDS total ~44.8 KB -> 3 blocks/CU.

#define DIN     512
#define BK      32
#define MT      32            // rows per block
#define THREADS 256
#define NCHUNK  (DIN / BK)    // 16
#define ASTR    40            // A row stride in shorts (32 + 8 pad)
#define BSTR    40            // B row stride in shorts

typedef __attribute__((ext_vector_type(8))) short bf16x8;
typedef __attribute__((ext_vector_type(4))) float f32x4;

__device__ __forceinline__ short f2bf(float f) {
    unsigned u = __float_as_uint(f);
    u = u + 0x7fffu + ((u >> 16) & 1u);   // RNE
    return (short)(u >> 16);
}

__global__ void cvt_w1_kernel(const float* __restrict__ w, short* __restrict__ o) {
    int i = blockIdx.x * blockDim.x + threadIdx.x;   // 65536 threads, 4 elems each
    float4 v = ((const float4*)w)[i];
    short4 s;
    s.x = f2bf(v.x); s.y = f2bf(v.y); s.z = f2bf(v.z); s.w = f2bf(v.w);
    ((short4*)o)[i] = s;
}

template<bool WS>
__global__ __launch_bounds__(THREADS)
void fused_head_kernel(const float* __restrict__ x,
                       const float* __restrict__ W1f,
                       const short* __restrict__ W1h,
                       const float* __restrict__ b1,
                       const float* __restrict__ gamma,
                       const float* __restrict__ beta,
                       const float* __restrict__ Wout,
                       const float* __restrict__ bout,
                       float* __restrict__ out) {
    __shared__ __align__(16) short As[MT * ASTR];     // 2560 B
    __shared__ __align__(16) short Bs[DIN * BSTR];    // 40960 B
    __shared__ float redS[MT][4];
    __shared__ float redQ[MT][4];
    __shared__ float meanA[MT];
    __shared__ float rstdA[MT];

    const int tid  = threadIdx.x;
    const int w    = tid >> 6;        // wave 0..3
    const int lane = tid & 63;
    const int q    = lane >> 4;       // quad 0..3
    const int l15  = lane & 15;

    const int m0 = blockIdx.x * MT;
    const int bb = m0 >> 9;           // batch index
    const int t0 = m0 & 511;          // first t of this block
    const float* xbase = x + (size_t)(bb * 513 + t0) * DIN;

    // staging index maps
    const int ar  = tid >> 3;         // A: row 0..31
    const int ak  = (tid & 7) * 4;    // A: k offset (4 floats)
    const int bn0 = tid >> 2;         // B(ws): n base 0..63
    const int bk8 = (tid & 3) * 8;    // B(ws): k offset (8 bf16)
    const int bnf = tid >> 3;         // B(f32): n base 0..31
    const int bkf = (tid & 7) * 4;    // B(f32): k offset (4 floats)

    f32x4 acc[2][8];
#pragma unroll
    for (int i = 0; i < 2; ++i)
#pragma unroll
        for (int j = 0; j < 8; ++j)
            acc[i][j] = (f32x4){0.f, 0.f, 0.f, 0.f};

    float4 aReg;
    uint4  bReg[8];

    // prologue: issue chunk-0 loads
    aReg = *(const float4*)(xbase + ar * DIN + ak);
    if (WS) {
#pragma unroll
        for (int p = 0; p < 8; ++p)
            bReg[p] = *(const uint4*)(W1h + (size_t)(bn0 + 64 * p) * DIN + bk8);
    }

    for (int c = 0; c < NCHUNK; ++c) {
        __syncthreads();   // previous compute done reading LDS
        // ---- store staged regs -> LDS (s_waitcnt vmcnt here) ----
        {
            short4 a4;
            a4.x = f2bf(aReg.x); a4.y = f2bf(aReg.y);
            a4.z = f2bf(aReg.z); a4.w = f2bf(aReg.w);
            *(short4*)(&As[ar * ASTR + ak]) = a4;
        }
        if (WS) {
#pragma unroll
            for (int p = 0; p < 8; ++p)
                *(uint4*)(&Bs[(bn0 + 64 * p) * BSTR + bk8]) = bReg[p];
        } else {
            const float* src = W1f + c * BK + bkf;
#pragma unroll
            for (int p = 0; p < 16; ++p) {
                float4 v = *(const float4*)(src + (size_t)(bnf + 32 * p) * DIN);
                short4 s4;
                s4.x = f2bf(v.x); s4.y = f2bf(v.y);
                s4.z = f2bf(v.z); s4.w = f2bf(v.w);
                *(short4*)(&Bs[(bnf + 32 * p) * BSTR + bkf]) = s4;
            }
        }
        __syncthreads();   // staging visible to all

        // ---- issue next chunk's global loads (in flight during MFMA) ----
        if (c + 1 < NCHUNK) {
            const int k0 = (c + 1) * BK;
            aReg = *(const float4*)(xbase + ar * DIN + k0 + ak);
            if (WS) {
#pragma unroll
                for (int p = 0; p < 8; ++p)
                    bReg[p] = *(const uint4*)(W1h + (size_t)(bn0 + 64 * p) * DIN + k0 + bk8);
            }
        }

        // ---- compute: 16 MFMAs ----
        bf16x8 af[2], bfr[8];
        const short* Ap = As + l15 * ASTR + q * 8;
#pragma unroll
        for (int ti = 0; ti < 2; ++ti)
            af[ti] = *(const bf16x8*)(Ap + ti * 16 * ASTR);
        const short* Bp = Bs + (w * 128 + l15) * BSTR + q * 8;
#pragma unroll
        for (int tj = 0; tj < 8; ++tj)
            bfr[tj] = *(const bf16x8*)(Bp + tj * 16 * BSTR);
#pragma unroll
        for (int ti = 0; ti < 2; ++ti)
#pragma unroll
            for (int tj = 0; tj < 8; ++tj)
                acc[ti][tj] = __builtin_amdgcn_mfma_f32_16x16x32_bf16(
                    af[ti], bfr[tj], acc[ti][tj], 0, 0, 0);
    }

    // ================= epilogue =================
    // per-lane column params (col = 128*w + 16*tj + l15, same for all rows)
    float b1v[8], gv[8], bv[8];
    const int cb = w * 128 + l15;
#pragma unroll
    for (int tj = 0; tj < 8; ++tj) {
        int col = cb + tj * 16;
        b1v[tj] = b1[col];
        gv[tj]  = gamma[col];
        bv[tj]  = beta[col];
    }

    // pass 1: row sums / sumsq.  C layout: col = l15, row = q*4 + r.
#pragma unroll
    for (int ti = 0; ti < 2; ++ti)
#pragma unroll
        for (int r = 0; r < 4; ++r) {
            int row = ti * 16 + q * 4 + r;
            float s = 0.f, s2 = 0.f;
#pragma unroll
            for (int tj = 0; tj < 8; ++tj) {
                float v = acc[ti][tj][r] + b1v[tj];
                s += v; s2 += v * v;
            }
#pragma unroll
            for (int m = 1; m < 16; m <<= 1) {
                s  += __shfl_xor(s,  m, 64);
                s2 += __shfl_xor(s2, m, 64);
            }
            if (l15 == 0) { redS[row][w] = s; redQ[row][w] = s2; }
        }
    __syncthreads();
    if (tid < MT) {
        float s  = redS[tid][0] + redS[tid][1] + redS[tid][2] + redS[tid][3];
        float s2 = redQ[tid][0] + redQ[tid][1] + redQ[tid][2] + redQ[tid][3];
        float mean = s * (1.f / DIN);
        float var  = s2 * (1.f / DIN) - mean * mean;
        meanA[tid] = mean;
        rstdA[tid] = rsqrtf(fmaxf(var, 0.f) + 1e-5f);
    }
    __syncthreads();

    // pass 2: normalize + relu + dot with Wout[t]
#pragma unroll
    for (int ti = 0; ti < 2; ++ti)
#pragma unroll
        for (int r = 0; r < 4; ++r) {
            int row = ti * 16 + q * 4 + r;
            float mean = meanA[row], rs = rstdA[row];
            const float* wrow = Wout + (size_t)(t0 + row) * DIN + cb;
            float s = 0.f;
#pragma unroll
            for (int tj = 0; tj < 8; ++tj) {
                float v = acc[ti][tj][r] + b1v[tj];
                v = (v - mean) * rs * gv[tj] + bv[tj];
                v = fmaxf(v, 0.f);
                s += v * wrow[tj * 16];
            }
#pragma unroll
            for (int m = 1; m < 16; m <<= 1)
                s += __shfl_xor(s, m, 64);
            if (l15 == 0) redS[row][w] = s;
        }
    __syncthreads();
    if (tid < MT)
        out[m0 + tid] = redS[tid][0] + redS[tid][1] + redS[tid][2] + redS[tid][3]
                        + bout[t0 + tid];
}

extern "C" void kernel_launch(void* const* d_in, const int* in_sizes, int n_in,
                              void* d_out, int out_size, void* d_ws, size_t ws_size,
                              hipStream_t stream) {
    const float* x     = (const float*)d_in[0];
    const float* W1    = (const float*)d_in[1];
    const float* b1    = (const float*)d_in[2];
    const float* gamma = (const float*)d_in[3];
    const float* beta  = (const float*)d_in[4];
    const float* Wout  = (const float*)d_in[5];
    const float* bout  = (const float*)d_in[6];
    float* out = (float*)d_out;

    const int M = 256 * 512;
    dim3 grid(M / MT), block(THREADS);

    if (ws_size >= (size_t)(DIN * DIN) * sizeof(short)) {
        short* W1h = (short*)d_ws;
        cvt_w1_kernel<<<DIN * DIN / (256 * 4), 256, 0, stream>>>(W1, W1h);
        fused_head_kernel<true><<<grid, block, 0, stream>>>(
            x, W1, W1h, b1, gamma, beta, Wout, bout, out);
    } else {
        fused_head_kernel<false><<<grid, block, 0, stream>>>(
            x, W1, nullptr, b1, gamma, beta, Wout, bout, out);
    }
}

// Round 2
// 435.064 us; speedup vs baseline: 2.3146x; 2.3146x over previous
//
#include <hip/hip_runtime.h>

// Fused ReconstructionHead: h = x[:, :-1] @ W1^T + b1; LayerNorm*gamma+beta;
// relu; out[b,t] = dot(h, Wout[t]) + bout[t].  M = 131072 rows, K = N = 512.
//
// R2 changes vs R1 (760 us, 786 MB spill writes):
//  - B staging via global_load_lds width-16 DMA (no bReg prefetch regs, no
//    VALU staging, conflict-free LDS writes)
//  - MT=64, 512 threads, wave tile 32x128 -> W1 L2 traffic halved
//  - __launch_bounds__(512,2): 256-VGPR cap, no spills, 2 blocks/CU

#define DIN     512
#define BK      32
#define MT      64            // rows per block
#define THREADS 512           // 8 waves
#define NCHUNK  (DIN / BK)    // 16
#define ASTR    40            // A row stride in shorts (32 + 8 pad; VALU-written)
#define BSTR    32            // B row stride in shorts (unpadded: DMA target)

typedef __attribute__((ext_vector_type(8))) short bf16x8;
typedef __attribute__((ext_vector_type(4))) float f32x4;

__device__ __forceinline__ short f2bf(float f) {
    unsigned u = __float_as_uint(f);
    u = u + 0x7fffu + ((u >> 16) & 1u);   // RNE
    return (short)(u >> 16);
}

__device__ __forceinline__ void gload_lds16(const void* g, void* l) {
    __builtin_amdgcn_global_load_lds(
        (const __attribute__((address_space(1))) unsigned int*)g,
        (__attribute__((address_space(3))) unsigned int*)l,
        16, 0, 0);
}

__global__ void cvt_w1_kernel(const float* __restrict__ w, short* __restrict__ o) {
    int i = blockIdx.x * blockDim.x + threadIdx.x;   // 65536 threads, 4 elems each
    float4 v = ((const float4*)w)[i];
    short4 s;
    s.x = f2bf(v.x); s.y = f2bf(v.y); s.z = f2bf(v.z); s.w = f2bf(v.w);
    ((short4*)o)[i] = s;
}

template<bool WS>
__global__ __launch_bounds__(THREADS, 2)
void fused_head_kernel(const float* __restrict__ x,
                       const float* __restrict__ W1f,
                       const short* __restrict__ W1h,
                       const float* __restrict__ b1,
                       const float* __restrict__ gamma,
                       const float* __restrict__ beta,
                       const float* __restrict__ Wout,
                       const float* __restrict__ bout,
                       float* __restrict__ out) {
    __shared__ __align__(16) short As[MT * ASTR];     // 5120 B
    __shared__ __align__(16) short Bs[DIN * BSTR];    // 32768 B
    __shared__ float redS[MT][4];
    __shared__ float redQ[MT][4];
    __shared__ float meanA[MT];
    __shared__ float rstdA[MT];

    const int tid  = threadIdx.x;
    const int w    = tid >> 6;        // wave 0..7
    const int lane = tid & 63;
    const int q    = lane >> 4;       // quad 0..3
    const int l15  = lane & 15;
    const int rg   = w >> 2;          // row group 0..1 (rows rg*32 .. +32)
    const int cg   = w & 3;           // col group 0..3 (cols cg*128 .. +128)

    const int m0 = blockIdx.x * MT;
    const int bb = m0 >> 9;           // batch index
    const int t0 = m0 & 511;          // first t of this block (64 | 512)
    const float* xbase = x + (size_t)(bb * 513 + t0) * DIN;

    // A staging map: 512 threads cover 64 rows x 32 k fp32 (one float4 each)
    const int ar = tid >> 3;          // row 0..63
    const int ak = (tid & 7) * 4;     // k offset (4 floats)

    // B DMA map: wave w stages rows [w*64, w*64+64); instr j covers 16 rows.
    // lane i -> row w*64 + j*16 + (i>>2), k-shorts (i&3)*8; lds lane offset i*16B.
    const short* bG = W1h + (size_t)(w * 64 + (lane >> 2)) * DIN + (lane & 3) * 8;
    short* bL = Bs + (w * 64) * BSTR;

    f32x4 acc[2][8];
#pragma unroll
    for (int i = 0; i < 2; ++i)
#pragma unroll
        for (int j = 0; j < 8; ++j)
            acc[i][j] = (f32x4){0.f, 0.f, 0.f, 0.f};

    float4 aReg = *(const float4*)(xbase + ar * DIN + ak);

    for (int c = 0; c < NCHUNK; ++c) {
        __syncthreads();   // previous compute done reading LDS
        {   // A: regs (prefetched) -> bf16 -> LDS
            short4 a4;
            a4.x = f2bf(aReg.x); a4.y = f2bf(aReg.y);
            a4.z = f2bf(aReg.z); a4.w = f2bf(aReg.w);
            *(short4*)(&As[ar * ASTR + ak]) = a4;
        }
        if (WS) {
            // B: async DMA global->LDS, 4 x (64 lanes x 16 B) per wave
#pragma unroll
            for (int j = 0; j < 4; ++j)
                gload_lds16(bG + (size_t)(j * 16) * DIN + c * BK,
                            bL + j * 16 * BSTR);
        } else {
            // fallback: fp32 W1 -> bf16 via VALU (one row per thread)
            const float* src = W1f + (size_t)tid * DIN + c * BK;
#pragma unroll
            for (int p = 0; p < 8; ++p) {
                float4 v = *(const float4*)(src + p * 4);
                short4 s4;
                s4.x = f2bf(v.x); s4.y = f2bf(v.y);
                s4.z = f2bf(v.z); s4.w = f2bf(v.w);
                *(short4*)(&Bs[tid * BSTR + p * 4]) = s4;
            }
        }
        __syncthreads();   // drains vmcnt (DMA) + lgkmcnt (A stores)

        // prefetch next A chunk while MFMAs run
        if (c + 1 < NCHUNK)
            aReg = *(const float4*)(xbase + ar * DIN + (c + 1) * BK + ak);

        // fragments + 16 MFMAs
        bf16x8 af[2], bfr[8];
        const short* Ap = As + (rg * 32 + l15) * ASTR + q * 8;
        af[0] = *(const bf16x8*)Ap;
        af[1] = *(const bf16x8*)(Ap + 16 * ASTR);
        const short* Bp = Bs + (cg * 128 + l15) * BSTR + q * 8;
#pragma unroll
        for (int tj = 0; tj < 8; ++tj)
            bfr[tj] = *(const bf16x8*)(Bp + tj * 16 * BSTR);
#pragma unroll
        for (int ti = 0; ti < 2; ++ti)
#pragma unroll
            for (int tj = 0; tj < 8; ++tj)
                acc[ti][tj] = __builtin_amdgcn_mfma_f32_16x16x32_bf16(
                    af[ti], bfr[tj], acc[ti][tj], 0, 0, 0);
    }

    // ================= epilogue =================
    float b1v[8], gv[8], bv[8];
    const int cb = cg * 128 + l15;
#pragma unroll
    for (int tj = 0; tj < 8; ++tj) {
        int col = cb + tj * 16;
        b1v[tj] = b1[col];
        gv[tj]  = gamma[col];
        bv[tj]  = beta[col];
    }

    // pass 1: row sums / sumsq.  C layout: col = l15 (within 16-col tile tj),
    // row = rg*32 + ti*16 + q*4 + r.
#pragma unroll
    for (int ti = 0; ti < 2; ++ti)
#pragma unroll
        for (int r = 0; r < 4; ++r) {
            int row = rg * 32 + ti * 16 + q * 4 + r;
            float s = 0.f, s2 = 0.f;
#pragma unroll
            for (int tj = 0; tj < 8; ++tj) {
                float v = acc[ti][tj][r] + b1v[tj];
                s += v; s2 += v * v;
            }
#pragma unroll
            for (int m = 1; m < 16; m <<= 1) {
                s  += __shfl_xor(s,  m, 64);
                s2 += __shfl_xor(s2, m, 64);
            }
            if (l15 == 0) { redS[row][cg] = s; redQ[row][cg] = s2; }
        }
    __syncthreads();
    if (tid < MT) {
        float s  = redS[tid][0] + redS[tid][1] + redS[tid][2] + redS[tid][3];
        float s2 = redQ[tid][0] + redQ[tid][1] + redQ[tid][2] + redQ[tid][3];
        float mean = s * (1.f / DIN);
        float var  = s2 * (1.f / DIN) - mean * mean;
        meanA[tid] = mean;
        rstdA[tid] = rsqrtf(fmaxf(var, 0.f) + 1e-5f);
    }
    __syncthreads();

    // pass 2: normalize + relu + dot with Wout[t]
#pragma unroll
    for (int ti = 0; ti < 2; ++ti)
#pragma unroll
        for (int r = 0; r < 4; ++r) {
            int row = rg * 32 + ti * 16 + q * 4 + r;
            float mean = meanA[row], rs = rstdA[row];
            const float* wrow = Wout + (size_t)(t0 + row) * DIN + cb;
            float s = 0.f;
#pragma unroll
            for (int tj = 0; tj < 8; ++tj) {
                float v = acc[ti][tj][r] + b1v[tj];
                v = (v - mean) * rs * gv[tj] + bv[tj];
                v = fmaxf(v, 0.f);
                s += v * wrow[tj * 16];
            }
#pragma unroll
            for (int m = 1; m < 16; m <<= 1)
                s += __shfl_xor(s, m, 64);
            if (l15 == 0) redS[row][cg] = s;
        }
    __syncthreads();
    if (tid < MT)
        out[m0 + tid] = redS[tid][0] + redS[tid][1] + redS[tid][2] + redS[tid][3]
                        + bout[t0 + tid];
}

extern "C" void kernel_launch(void* const* d_in, const int* in_sizes, int n_in,
                              void* d_out, int out_size, void* d_ws, size_t ws_size,
                              hipStream_t stream) {
    const float* x     = (const float*)d_in[0];
    const float* W1    = (const float*)d_in[1];
    const float* b1    = (const float*)d_in[2];
    const float* gamma = (const float*)d_in[3];
    const float* beta  = (const float*)d_in[4];
    const float* Wout  = (const float*)d_in[5];
    const float* bout  = (const float*)d_in[6];
    float* out = (float*)d_out;

    const int M = 256 * 512;
    dim3 grid(M / MT), block(THREADS);

    if (ws_size >= (size_t)(DIN * DIN) * sizeof(short)) {
        short* W1h = (short*)d_ws;
        cvt_w1_kernel<<<DIN * DIN / (256 * 4), 256, 0, stream>>>(W1, W1h);
        fused_head_kernel<true><<<grid, block, 0, stream>>>(
            x, W1, W1h, b1, gamma, beta, Wout, bout, out);
    } else {
        fused_head_kernel<false><<<grid, block, 0, stream>>>(
            x, W1, nullptr, b1, gamma, beta, Wout, bout, out);
    }
}